// Round 14
// baseline (208.409 us; speedup 1.0000x reference)
//
#include <hip/hip_runtime.h>
#include <stdint.h>

#define SEQ 4096
#define NHEAD 16
#define HDIM 64

typedef __attribute__((ext_vector_type(4))) float f32x4;
typedef __attribute__((ext_vector_type(16))) float f32x16;
typedef __attribute__((ext_vector_type(8))) __bf16 bf16x8;
typedef __attribute__((ext_vector_type(8))) unsigned short u16x8;
typedef __attribute__((ext_vector_type(4))) unsigned short u16x4;
typedef __attribute__((ext_vector_type(4))) unsigned int u32x4;

static __device__ __forceinline__ float bf2f(unsigned short u) {
    unsigned int x = ((unsigned int)u) << 16;
    return __builtin_bit_cast(float, x);
}
static __device__ __forceinline__ unsigned short f2bf(float f) {
    unsigned int u = __builtin_bit_cast(unsigned int, f);
    u += 0x7FFFu + ((u >> 16) & 1u);   // RNE
    return (unsigned short)(u >> 16);
}
static __device__ __forceinline__ f32x4 mfma_bf16_16x16x32(u16x8 a, u16x8 b, f32x4 c) {
    return __builtin_amdgcn_mfma_f32_16x16x32_bf16(
        __builtin_bit_cast(bf16x8, a), __builtin_bit_cast(bf16x8, b), c, 0, 0, 0);
}
static __device__ __forceinline__ f32x16 mfma_bf16_32x32x16(u16x8 a, u16x8 b, f32x16 c) {
    return __builtin_amdgcn_mfma_f32_32x32x16_bf16(
        __builtin_bit_cast(bf16x8, a), __builtin_bit_cast(bf16x8, b), c, 0, 0, 0);
}
static __device__ __forceinline__ void gload_lds16(const void* g, void* l) {
    __builtin_amdgcn_global_load_lds(
        (__attribute__((address_space(1))) unsigned int*)g,
        (__attribute__((address_space(3))) unsigned int*)l,
        16, 0, 0);
}
static __device__ __forceinline__ unsigned int cvtpk_bf16(float lo, float hi) {
    unsigned int r;
    asm("v_cvt_pk_bf16_f32 %0, %1, %2" : "=v"(r) : "v"(lo), "v"(hi));
    return r;
}

// ---------------- fused f32 -> bf16 convert (x, qkv_w, proj_w) ----------------
__global__ void cvt3_kernel(const float* __restrict__ s0, unsigned short* __restrict__ d0, int n0q,
                            const float* __restrict__ s1, unsigned short* __restrict__ d1, int n1q,
                            const float* __restrict__ s2, unsigned short* __restrict__ d2, int n2q)
{
    const int stride = gridDim.x * blockDim.x;
    const int total = n0q + n1q + n2q;
    for (int i = blockIdx.x * blockDim.x + threadIdx.x; i < total; i += stride) {
        const float* src; unsigned short* dst; int j;
        if (i < n0q)            { src = s0; dst = d0; j = i; }
        else if (i < n0q + n1q) { src = s1; dst = d1; j = i - n0q; }
        else                    { src = s2; dst = d2; j = i - n0q - n1q; }
        f32x4 v = *(const f32x4*)(src + (size_t)j * 4);
        u16x4 o;
#pragma unroll
        for (int k = 0; k < 4; k++) o[k] = f2bf(v[k]);
        *(u16x4*)(dst + (size_t)j * 4) = o;
    }
}

// ---------------- GEMM: C[M][N] = A[M][K(lda)] * B[N][K]^T ----------------
// r14: chunk-XOR LDS swizzle (both-sides involution, proven in attn r2):
// staging keeps the linear LDS dest required by global_load_lds and applies
// the inverse permutation on the per-lane GLOBAL source chunk; ds_read_b128
// applies the same XOR on the read offset. LDS row r chunk c holds global
// chunk c^(r&7), read at (kc/8)^(r&7) -> retrieves global chunk kc/8.
// 16 lanes (l15) previously hit the same 16B chunk position -> 16-way bank
// serialization (m98: 1.7e7 conflicts on this structure).
template<int OUT_BF16>
__global__ __launch_bounds__(256) void gemm_bt_kernel(
    const unsigned short* __restrict__ A,
    const unsigned short* __restrict__ B,
    void* __restrict__ Cv,
    int M, int N, int K, int lda)
{
    __shared__ __align__(16) unsigned short As[128 * 64];
    __shared__ __align__(16) unsigned short Bs[128 * 64];
    const int tid = threadIdx.x;
    const int lane = tid & 63;
    const int wave = tid >> 6;
    const int wm = (wave >> 1) * 64;
    const int wn = (wave & 1) * 64;
    const int bm = blockIdx.y * 128, bn = blockIdx.x * 128;
    const int l15 = lane & 15, l4 = lane >> 4;
    const int rsw = (l15 & 7) * 8;          // read-side swizzle

    f32x4 acc[4][4];
#pragma unroll
    for (int i = 0; i < 4; i++)
#pragma unroll
        for (int j = 0; j < 4; j++) acc[i][j] = (f32x4){0.f, 0.f, 0.f, 0.f};

    const int srow = tid >> 3;              // 0..31 (segment-local row)
    const int scs = ((tid & 7) * 8) ^ ((srow & 7) * 8);   // inverse-swizzled source chunk
    const unsigned short* Ab = A + (size_t)(bm + srow) * lda + scs;
    const unsigned short* Bb = B + (size_t)(bn + srow) * K + scs;

    for (int kt = 0; kt < K; kt += 64) {
#pragma unroll
        for (int ci = 0; ci < 4; ci++)
            gload_lds16(Ab + (size_t)ci * 32 * lda + kt, &As[ci * 2048 + tid * 8]);
#pragma unroll
        for (int ci = 0; ci < 4; ci++)
            gload_lds16(Bb + (size_t)ci * 32 * K + kt, &Bs[ci * 2048 + tid * 8]);
        __syncthreads();
#pragma unroll
        for (int ks = 0; ks < 2; ks++) {
            const int kc = (ks * 32 + l4 * 8) ^ rsw;
            u16x8 af[4], bfr[4];
#pragma unroll
            for (int i = 0; i < 4; i++)
                af[i] = *(const u16x8*)&As[(wm + i * 16 + l15) * 64 + kc];
#pragma unroll
            for (int j = 0; j < 4; j++)
                bfr[j] = *(const u16x8*)&Bs[(wn + j * 16 + l15) * 64 + kc];
#pragma unroll
            for (int i = 0; i < 4; i++)
#pragma unroll
                for (int j = 0; j < 4; j++)
                    acc[i][j] = mfma_bf16_16x16x32(af[i], bfr[j], acc[i][j]);
        }
        __syncthreads();
    }

    const int orow = bm + wm + l4 * 4;
    const int ocol = bn + wn + l15;
#pragma unroll
    for (int i = 0; i < 4; i++)
#pragma unroll
        for (int j = 0; j < 4; j++)
#pragma unroll
            for (int r = 0; r < 4; r++) {
                size_t idx = (size_t)(orow + i * 16 + r) * N + (ocol + j * 16);
                if (OUT_BF16) ((unsigned short*)Cv)[idx] = f2bf(acc[i][j][r]);
                else          ((float*)Cv)[idx] = acc[i][j][r];
            }
}

// -------- RMS-norm + RoPE + lambda*v + fused V transpose --------
__global__ __launch_bounds__(256) void rope_norm_tr_kernel(
    const unsigned short* __restrict__ qkv,   // [SEQ][3072] bf16
    const float* __restrict__ lambdas,
    unsigned short* __restrict__ qh,          // [16][SEQ][64]
    unsigned short* __restrict__ kh,
    unsigned short* __restrict__ vT)          // [16][64][SEQ]
{
    __shared__ __align__(16) unsigned short tile[64][72];
    const int h = blockIdx.x >> 6;
    const int tt = (blockIdx.x & 63) * 64;
    const int lane = threadIdx.x & 63;
    const int wave = threadIdx.x >> 6;
    const float lam = lambdas[0];
    const int i = lane & 31;
    const float w = (i < 16) ? exp2f(-(10.0f / 15.0f) * (float)i) : 0.0f;

#pragma unroll 1
    for (int it = 0; it < 16; it++) {
        const int tl = it * 4 + wave;             // 0..63
        const int t = tt + tl;
        const size_t base = (size_t)t * 3072 + h * 64 + lane;
        float q = bf2f(qkv[base]);
        float k = bf2f(qkv[base + 1024]);
        float v = bf2f(qkv[base + 2048]);
        float sq = q * q, sk = k * k;
#pragma unroll
        for (int m = 1; m < 64; m <<= 1) {
            sq += __shfl_xor(sq, m);
            sk += __shfl_xor(sk, m);
        }
        q *= rsqrtf(sq * (1.0f / 64.0f) + 1e-6f);
        k *= rsqrtf(sk * (1.0f / 64.0f) + 1e-6f);
        float th = (float)t * w;
        float c = cosf(th), s = sinf(th);
        float qp = __shfl_xor(q, 32);
        float kp = __shfl_xor(k, 32);
        float sg = (lane < 32) ? s : -s;
        float qo = (q * c + qp * sg) * 0.1803368801111244f;  // 0.125 * log2(e)
        float ko = k * c + kp * sg;
        const size_t o = ((size_t)h * SEQ + t) * 64 + lane;
        qh[o] = f2bf(qo);
        kh[o] = f2bf(ko);
        tile[tl][lane] = f2bf(v * lam);
    }
    __syncthreads();
    const int tid = threadIdx.x;
    const int row = tid >> 2;          // d index 0..63
    const int c0 = (tid & 3) * 16;     // t-local 0,16,32,48
    u16x8 o0, o1;
#pragma unroll
    for (int j = 0; j < 8; j++) { o0[j] = tile[c0 + j][row]; o1[j] = tile[c0 + 8 + j][row]; }
    u16x8* dst = (u16x8*)(vT + ((size_t)h * 64 + row) * SEQ + tt + c0);
    dst[0] = o0; dst[1] = o1;
}

// ---------------- causal flash attention, swapped-QK^T 32x32 ----------------
// r12 verified body; kv-slice s is now a kernel ARGUMENT and the kernel is
// launched twice (s=0, s=1) so the GEMM dispatches surface in rocprof's
// top-5 (attn monopolized all slots for 12 rounds; ~36us of runtime is
// unaccounted and likely in the GEMMs). Each launch: 512 blocks, uniform 33
// tiles/block, 2 blocks/CU — aggregate schedule unchanged.
__global__ __launch_bounds__(256, 2) void attn_kernel(
    const unsigned short* __restrict__ qh,   // [16][SEQ][64], scaled 0.125*log2e
    const unsigned short* __restrict__ kh,   // [16][SEQ][64]
    const unsigned short* __restrict__ vT,   // [16][64][SEQ]
    float* __restrict__ acc,                 // [SEQ][1024] f32 (zeroed)
    float* __restrict__ lacc,                // [SEQ][16] f32 (zeroed)
    const int s)                             // kv half 0..1
{
    __shared__ __align__(16) unsigned short Ks[2][64 * 64];
    __shared__ __align__(16) unsigned short Vs[2][64 * 64];   // [d][kv]
    const int h = blockIdx.x;
    const int qp = blockIdx.y;        // 0..15, paired with 31-qp
    const int tid = threadIdx.x;
    const int lane = tid & 63;
    const int wave = tid >> 6;        // 0..3
    const int l31 = lane & 31;
    const int hi = lane >> 5;
    const int r7 = l31 & 7;

    const unsigned short* Kb = kh + (size_t)h * SEQ * 64;
    const unsigned short* Vb = vT + (size_t)h * 64 * SEQ;

    u16x8 ones;
#pragma unroll
    for (int j = 0; j < 8; j++) ones[j] = 0x3F80;   // bf16 1.0

    const int sr = tid >> 3;                    // 0..31
    const int scs = ((tid & 7) * 8) ^ ((sr & 7) * 8);

#pragma unroll 1
    for (int ph = 0; ph < 2; ph++) {
        const int qtp = ph ? (31 - qp) : qp;
        const int nt = 2 * qtp + 2;
        const int t0 = (nt * s) >> 1;
        const int t1 = (nt * (s + 1)) >> 1;
        const int q0w = qtp * 128 + wave * 32;

        u16x8 qf[4];
        {
            const unsigned short* qb = qh + ((size_t)h * SEQ + q0w + l31) * 64 + hi * 8;
#pragma unroll
            for (int c = 0; c < 4; c++) qf[c] = *(const u16x8*)(qb + c * 16);
        }

        f32x16 o0 = {}, o1 = {}, lA = {};

        const unsigned short* kst = Kb + (size_t)(t0 * 64 + sr) * 64 + scs;
        const unsigned short* vst = Vb + (size_t)sr * SEQ + t0 * 64 + scs;

        gload_lds16(kst,            &Ks[0][tid * 8]);
        gload_lds16(kst + 32 * 64,  &Ks[0][2048 + tid * 8]);
        gload_lds16(vst,            &Vs[0][tid * 8]);
        gload_lds16(vst + 32 * SEQ, &Vs[0][2048 + tid * 8]);
        kst += 64 * 64;
        vst += 64;
        __syncthreads();

        int cur = 0;
        for (int kt = t0; kt < t1; kt++) {
            const int kv0 = kt * 64;
            if (kt + 1 < t1) {
                gload_lds16(kst,            &Ks[cur ^ 1][tid * 8]);
                gload_lds16(kst + 32 * 64,  &Ks[cur ^ 1][2048 + tid * 8]);
                gload_lds16(vst,            &Vs[cur ^ 1][tid * 8]);
                gload_lds16(vst + 32 * SEQ, &Vs[cur ^ 1][2048 + tid * 8]);
            }
            kst += 64 * 64;
            vst += 64;
            if (kv0 <= q0w + 31) {
                const unsigned short* ks0 = &Ks[cur][l31 * 64];
                const unsigned short* vs0 = &Vs[cur][l31 * 64];
                const unsigned short* ks1 = ks0 + 32 * 64;
                const unsigned short* vs1 = vs0 + 32 * 64;
                const bool half2 = (kv0 + 32 <= q0w + 31);
                const int q = q0w + l31;

                // ---------- S-half 0: kv rows kv0 .. kv0+31 ----------
                {
                    f32x16 st = {};
                    __builtin_amdgcn_s_setprio(1);
#pragma unroll
                    for (int c = 0; c < 4; c++) {
                        const int off = ((c * 2 + hi) ^ r7) * 8;
                        st = mfma_bf16_32x32x16(*(const u16x8*)(ks0 + off), qf[c], st);
                    }
                    __builtin_amdgcn_s_setprio(0);
                    if (kv0 + 31 > q0w) {
#pragma unroll
                        for (int r = 0; r < 16; r++) {
                            const int crow = (r & 3) + 8 * (r >> 2) + 4 * hi;
                            if (kv0 + crow > q) st[r] = -1e30f;
                        }
                    }
#pragma unroll
                    for (int r = 0; r < 16; r++) st[r] = exp2f(st[r]);

                    u16x8 paf[2];
#pragma unroll
                    for (int kk = 0; kk < 2; kk++) {
                        const int rb = kk * 8;
                        unsigned int a0 = cvtpk_bf16(st[rb + 0], st[rb + 1]);
                        unsigned int a1 = cvtpk_bf16(st[rb + 2], st[rb + 3]);
                        unsigned int b0 = cvtpk_bf16(st[rb + 4], st[rb + 5]);
                        unsigned int b1 = cvtpk_bf16(st[rb + 6], st[rb + 7]);
                        asm("v_permlane32_swap_b32 %0, %1" : "+v"(a0), "+v"(b0));
                        asm("v_permlane32_swap_b32 %0, %1" : "+v"(a1), "+v"(b1));
                        u32x4 w;
                        w[0] = a0; w[1] = a1; w[2] = b0; w[3] = b1;
                        paf[kk] = __builtin_bit_cast(u16x8, w);
                    }
                    __builtin_amdgcn_s_setprio(1);
#pragma unroll
                    for (int kk = 0; kk < 2; kk++) {
                        const int off = ((kk * 2 + hi) ^ r7) * 8;
                        u16x8 v0 = *(const u16x8*)(vs0 + off);
                        u16x8 v1 = *(const u16x8*)(vs1 + off);
                        o0 = mfma_bf16_32x32x16(paf[kk], v0, o0);
                        o1 = mfma_bf16_32x32x16(paf[kk], v1, o1);
                        lA = mfma_bf16_32x32x16(paf[kk], ones, lA);
                    }
                    __builtin_amdgcn_s_setprio(0);
                }

                // ---------- S-half 1: kv rows kv0+32 .. kv0+63 ----------
                if (half2) {
                    f32x16 st = {};
                    __builtin_amdgcn_s_setprio(1);
#pragma unroll
                    for (int c = 0; c < 4; c++) {
                        const int off = ((c * 2 + hi) ^ r7) * 8;
                        st = mfma_bf16_32x32x16(*(const u16x8*)(ks1 + off), qf[c], st);
                    }
                    __builtin_amdgcn_s_setprio(0);
                    if (kv0 + 63 > q0w) {
#pragma unroll
                        for (int r = 0; r < 16; r++) {
                            const int crow = (r & 3) + 8 * (r >> 2) + 4 * hi;
                            if (kv0 + 32 + crow > q) st[r] = -1e30f;
                        }
                    }
#pragma unroll
                    for (int r = 0; r < 16; r++) st[r] = exp2f(st[r]);

                    u16x8 paf[2];
#pragma unroll
                    for (int kk = 0; kk < 2; kk++) {
                        const int rb = kk * 8;
                        unsigned int a0 = cvtpk_bf16(st[rb + 0], st[rb + 1]);
                        unsigned int a1 = cvtpk_bf16(st[rb + 2], st[rb + 3]);
                        unsigned int b0 = cvtpk_bf16(st[rb + 4], st[rb + 5]);
                        unsigned int b1 = cvtpk_bf16(st[rb + 6], st[rb + 7]);
                        asm("v_permlane32_swap_b32 %0, %1" : "+v"(a0), "+v"(b0));
                        asm("v_permlane32_swap_b32 %0, %1" : "+v"(a1), "+v"(b1));
                        u32x4 w;
                        w[0] = a0; w[1] = a1; w[2] = b0; w[3] = b1;
                        paf[kk] = __builtin_bit_cast(u16x8, w);
                    }
                    __builtin_amdgcn_s_setprio(1);
#pragma unroll
                    for (int kk = 0; kk < 2; kk++) {
                        const int off = (((kk + 2) * 2 + hi) ^ r7) * 8;
                        u16x8 v0 = *(const u16x8*)(vs0 + off);
                        u16x8 v1 = *(const u16x8*)(vs1 + off);
                        o0 = mfma_bf16_32x32x16(paf[kk], v0, o0);
                        o1 = mfma_bf16_32x32x16(paf[kk], v1, o1);
                        lA = mfma_bf16_32x32x16(paf[kk], ones, lA);
                    }
                    __builtin_amdgcn_s_setprio(0);
                }
            }
            __syncthreads();
            cur ^= 1;
        }

        // epilogue: atomic-accumulate raw partial (O, l) in f32.
        if (t0 * 64 <= q0w + 31) {
#pragma unroll
            for (int r = 0; r < 16; r++) {
                const int crow = (r & 3) + 8 * (r >> 2) + 4 * hi;
                float* row = acc + (size_t)(q0w + crow) * 1024 + h * 64;
                atomicAdd(row + l31,      o0[r]);
                atomicAdd(row + 32 + l31, o1[r]);
            }
            if (l31 == 0) {
#pragma unroll
                for (int r = 0; r < 16; r++) {
                    const int crow = (r & 3) + 8 * (r >> 2) + 4 * hi;
                    atomicAdd(lacc + (size_t)(q0w + crow) * 16 + h, lA[r]);
                }
            }
        }
    }
}

// ---------------- normalize: yb = bf16(acc / lacc) ----------------
__global__ __launch_bounds__(256) void norm_kernel(
    const float* __restrict__ acc, const float* __restrict__ lacc,
    unsigned short* __restrict__ yb)
{
    const int i = blockIdx.x * 256 + threadIdx.x;   // quad index, 1,048,576 total
    const int t = i >> 8;
    const int h = (i & 255) >> 4;
    const float inv = 1.0f / lacc[t * 16 + h];
    f32x4 v = *(const f32x4*)(acc + (size_t)i * 4);
    u16x4 o;
#pragma unroll
    for (int j = 0; j < 4; j++) o[j] = f2bf(v[j] * inv);
    *(u16x4*)(yb + (size_t)i * 4) = o;
}

extern "C" void kernel_launch(void* const* d_in, const int* in_sizes, int n_in,
                              void* d_out, int out_size, void* d_ws, size_t ws_size,
                              hipStream_t stream) {
    (void)in_sizes; (void)n_in; (void)out_size; (void)ws_size;
    const float* x       = (const float*)d_in[0];
    const float* qkv_w   = (const float*)d_in[1];
    const float* lambdas = (const float*)d_in[2];
    const float* proj_w  = (const float*)d_in[3];

    char* ws = (char*)d_ws;
    // layout; acc/lacc overlay x_bf+qkv_bf (dead before attn)
    unsigned short* x_bf   = (unsigned short*)(ws + 0);          //  8 MB [0,8M)
    unsigned short* qkv_bf = (unsigned short*)(ws + 8388608);    // 24 MB [8M,32M)
    unsigned short* qh     = (unsigned short*)(ws + 33554432);   //  8 MB
    unsigned short* kh     = (unsigned short*)(ws + 41943040);   //  8 MB
    unsigned short* vT     = (unsigned short*)(ws + 58720256);   //  8 MB
    unsigned short* wq_bf  = (unsigned short*)(ws + 67108864);   //  6 MB
    unsigned short* wp_bf  = (unsigned short*)(ws + 73400320);   //  2 MB
    unsigned short* yb     = (unsigned short*)(ws + 75497472);   //  8 MB
    float*          acc    = (float*)(ws + 0);                   // 16 MB [0,16.78M)
    float*          lacc   = (float*)(ws + 16777216);            // 256 KB

    cvt3_kernel<<<2048, 256, 0, stream>>>(x, x_bf, 1048576,
                                          qkv_w, wq_bf, 786432,
                                          proj_w, wp_bf, 262144);

    gemm_bt_kernel<1><<<dim3(24, 32), 256, 0, stream>>>(x_bf, wq_bf, qkv_bf, 4096, 3072, 1024, 1024);
    rope_norm_tr_kernel<<<1024, 256, 0, stream>>>(qkv_bf, lambdas, qh, kh, vT);

    // zero the f32 accumulators (x_bf/qkv_bf are dead now); capture-safe async
    hipMemsetAsync(ws, 0, 16777216 + 262144, stream);

    attn_kernel<<<dim3(16, 16), 256, 0, stream>>>(qh, kh, vT, acc, lacc, 0);
    attn_kernel<<<dim3(16, 16), 256, 0, stream>>>(qh, kh, vT, acc, lacc, 1);
    norm_kernel<<<4096, 256, 0, stream>>>(acc, lacc, yb);

    gemm_bt_kernel<0><<<dim3(8, 32), 256, 0, stream>>>(yb, wp_bf, d_out, 4096, 1024, 1024, 1024);
}

// Round 15
// 206.326 us; speedup vs baseline: 1.0101x; 1.0101x over previous
//
#include <hip/hip_runtime.h>
#include <stdint.h>

#define SEQ 4096
#define NHEAD 16
#define HDIM 64

typedef __attribute__((ext_vector_type(4))) float f32x4;
typedef __attribute__((ext_vector_type(16))) float f32x16;
typedef __attribute__((ext_vector_type(8))) __bf16 bf16x8;
typedef __attribute__((ext_vector_type(8))) unsigned short u16x8;
typedef __attribute__((ext_vector_type(4))) unsigned short u16x4;
typedef __attribute__((ext_vector_type(4))) unsigned int u32x4;

static __device__ __forceinline__ float bf2f(unsigned short u) {
    unsigned int x = ((unsigned int)u) << 16;
    return __builtin_bit_cast(float, x);
}
static __device__ __forceinline__ unsigned short f2bf(float f) {
    unsigned int u = __builtin_bit_cast(unsigned int, f);
    u += 0x7FFFu + ((u >> 16) & 1u);   // RNE
    return (unsigned short)(u >> 16);
}
static __device__ __forceinline__ f32x4 mfma_bf16_16x16x32(u16x8 a, u16x8 b, f32x4 c) {
    return __builtin_amdgcn_mfma_f32_16x16x32_bf16(
        __builtin_bit_cast(bf16x8, a), __builtin_bit_cast(bf16x8, b), c, 0, 0, 0);
}
static __device__ __forceinline__ f32x16 mfma_bf16_32x32x16(u16x8 a, u16x8 b, f32x16 c) {
    return __builtin_amdgcn_mfma_f32_32x32x16_bf16(
        __builtin_bit_cast(bf16x8, a), __builtin_bit_cast(bf16x8, b), c, 0, 0, 0);
}
static __device__ __forceinline__ void gload_lds16(const void* g, void* l) {
    __builtin_amdgcn_global_load_lds(
        (__attribute__((address_space(1))) unsigned int*)g,
        (__attribute__((address_space(3))) unsigned int*)l,
        16, 0, 0);
}
static __device__ __forceinline__ unsigned int cvtpk_bf16(float lo, float hi) {
    unsigned int r;
    asm("v_cvt_pk_bf16_f32 %0, %1, %2" : "=v"(r) : "v"(lo), "v"(hi));
    return r;
}

// ---------------- fused f32 -> bf16 convert (x, qkv_w, proj_w) ----------------
__global__ void cvt3_kernel(const float* __restrict__ s0, unsigned short* __restrict__ d0, int n0q,
                            const float* __restrict__ s1, unsigned short* __restrict__ d1, int n1q,
                            const float* __restrict__ s2, unsigned short* __restrict__ d2, int n2q)
{
    const int stride = gridDim.x * blockDim.x;
    const int total = n0q + n1q + n2q;
    for (int i = blockIdx.x * blockDim.x + threadIdx.x; i < total; i += stride) {
        const float* src; unsigned short* dst; int j;
        if (i < n0q)            { src = s0; dst = d0; j = i; }
        else if (i < n0q + n1q) { src = s1; dst = d1; j = i - n0q; }
        else                    { src = s2; dst = d2; j = i - n0q - n1q; }
        f32x4 v = *(const f32x4*)(src + (size_t)j * 4);
        u16x4 o;
#pragma unroll
        for (int k = 0; k < 4; k++) o[k] = f2bf(v[k]);
        *(u16x4*)(dst + (size_t)j * 4) = o;
    }
}

// ---------------- GEMM: C[M][N] = A[M][K(lda)] * B[N][K]^T ----------------
// ATOMIC=1: split-K — each blockIdx.z computes K/gridDim.z and atomicAdds
// its f32 partial into C (C must be zeroed; 2 contributors per element ->
// fp-add commutative -> bit-deterministic across replays).
template<int OUT_BF16, int ATOMIC>
__global__ __launch_bounds__(256) void gemm_bt_kernel(
    const unsigned short* __restrict__ A,
    const unsigned short* __restrict__ B,
    void* __restrict__ Cv,
    int M, int N, int K, int lda)
{
    __shared__ __align__(16) unsigned short As[128 * 64];
    __shared__ __align__(16) unsigned short Bs[128 * 64];
    const int tid = threadIdx.x;
    const int lane = tid & 63;
    const int wave = tid >> 6;
    const int wm = (wave >> 1) * 64;
    const int wn = (wave & 1) * 64;
    const int bm = blockIdx.y * 128, bn = blockIdx.x * 128;
    const int l15 = lane & 15, l4 = lane >> 4;

    const int kslice = K / gridDim.z;
    const int k0 = blockIdx.z * kslice;

    f32x4 acc[4][4];
#pragma unroll
    for (int i = 0; i < 4; i++)
#pragma unroll
        for (int j = 0; j < 4; j++) acc[i][j] = (f32x4){0.f, 0.f, 0.f, 0.f};

    const int srow = tid >> 3;
    const int scol = (tid & 7) * 8;
    const unsigned short* Ab = A + (size_t)(bm + srow) * lda + scol;
    const unsigned short* Bb = B + (size_t)(bn + srow) * K + scol;

    for (int kt = k0; kt < k0 + kslice; kt += 64) {
#pragma unroll
        for (int ci = 0; ci < 4; ci++)
            gload_lds16(Ab + (size_t)ci * 32 * lda + kt, &As[ci * 2048 + tid * 8]);
#pragma unroll
        for (int ci = 0; ci < 4; ci++)
            gload_lds16(Bb + (size_t)ci * 32 * K + kt, &Bs[ci * 2048 + tid * 8]);
        __syncthreads();
#pragma unroll
        for (int ks = 0; ks < 2; ks++) {
            const int kc = ks * 32 + l4 * 8;
            u16x8 af[4], bfr[4];
#pragma unroll
            for (int i = 0; i < 4; i++)
                af[i] = *(const u16x8*)&As[(wm + i * 16 + l15) * 64 + kc];
#pragma unroll
            for (int j = 0; j < 4; j++)
                bfr[j] = *(const u16x8*)&Bs[(wn + j * 16 + l15) * 64 + kc];
#pragma unroll
            for (int i = 0; i < 4; i++)
#pragma unroll
                for (int j = 0; j < 4; j++)
                    acc[i][j] = mfma_bf16_16x16x32(af[i], bfr[j], acc[i][j]);
        }
        __syncthreads();
    }

    const int orow = bm + wm + l4 * 4;
    const int ocol = bn + wn + l15;
#pragma unroll
    for (int i = 0; i < 4; i++)
#pragma unroll
        for (int j = 0; j < 4; j++)
#pragma unroll
            for (int r = 0; r < 4; r++) {
                size_t idx = (size_t)(orow + i * 16 + r) * N + (ocol + j * 16);
                if (ATOMIC)            atomicAdd(&((float*)Cv)[idx], acc[i][j][r]);
                else if (OUT_BF16)     ((unsigned short*)Cv)[idx] = f2bf(acc[i][j][r]);
                else                   ((float*)Cv)[idx] = acc[i][j][r];
            }
}

// ---------------- RMS-norm + RoPE + lambda*v ----------------
// Q pre-scaled by (1/sqrt(D)) * log2(e) so attention exp runs in exp2 domain.
__global__ __launch_bounds__(256) void rope_norm_kernel(
    const unsigned short* __restrict__ qkv,   // [SEQ][3072] bf16
    const float* __restrict__ lambdas,
    unsigned short* __restrict__ qh,          // [16][SEQ][64]
    unsigned short* __restrict__ kh,
    unsigned short* __restrict__ vh)
{
    const int lane = threadIdx.x & 63;
    const int wave = threadIdx.x >> 6;
    const int vec = blockIdx.x * 4 + wave;
    const int t = vec >> 4;
    const int h = vec & 15;
    const size_t base = (size_t)t * 3072 + h * 64 + lane;
    float q = bf2f(qkv[base]);
    float k = bf2f(qkv[base + 1024]);
    float v = bf2f(qkv[base + 2048]);
    float sq = q * q, sk = k * k;
#pragma unroll
    for (int m = 1; m < 64; m <<= 1) {
        sq += __shfl_xor(sq, m);
        sk += __shfl_xor(sk, m);
    }
    q *= rsqrtf(sq * (1.0f / 64.0f) + 1e-6f);
    k *= rsqrtf(sk * (1.0f / 64.0f) + 1e-6f);
    const int i = lane & 31;
    float w = (i < 16) ? exp2f(-(10.0f / 15.0f) * (float)i) : 0.0f;
    float th = (float)t * w;
    float c = cosf(th), s = sinf(th);
    float qp = __shfl_xor(q, 32);
    float kp = __shfl_xor(k, 32);
    float sg = (lane < 32) ? s : -s;
    float qo = (q * c + qp * sg) * 0.1803368801111244f;  // 0.125 * log2(e)
    float ko = k * c + kp * sg;
    float vo = v * lambdas[0];
    const size_t o = ((size_t)h * SEQ + t) * 64 + lane;
    qh[o] = f2bf(qo);
    kh[o] = f2bf(ko);
    vh[o] = f2bf(vo);
}

// ---------------- V transpose: [h][t][d] -> [h][d][t] ----------------
__global__ __launch_bounds__(256) void transpose_v_kernel(
    const unsigned short* __restrict__ vh, unsigned short* __restrict__ vT)
{
    __shared__ __align__(16) unsigned short tile[64][72];
    const int h = blockIdx.x >> 6;
    const int tt = (blockIdx.x & 63) * 64;
    const int tid = threadIdx.x;
    const int row = tid >> 2;
    const int c0 = (tid & 3) * 16;
    const u16x8* src = (const u16x8*)(vh + ((size_t)h * SEQ + tt + row) * 64 + c0);
    u16x8 a = src[0], b = src[1];
#pragma unroll
    for (int j = 0; j < 8; j++) { tile[row][c0 + j] = a[j]; tile[row][c0 + 8 + j] = b[j]; }
    __syncthreads();
    u16x8 o0, o1;
#pragma unroll
    for (int j = 0; j < 8; j++) { o0[j] = tile[c0 + j][row]; o1[j] = tile[c0 + 8 + j][row]; }
    u16x8* dst = (u16x8*)(vT + ((size_t)h * 64 + row) * SEQ + tt + c0);
    dst[0] = o0; dst[1] = o1;
}

// ---------------- causal flash attention, swapped-QK^T 32x32 ----------------
// r10 verified structure (best measured: 79.9us attn, 190.8us total):
// block = (head, q-pair, kv-third); 256 thr = 4 waves x 32 q-rows; the two
// 32-kv S-halves processed sequentially (lower register pressure); running
// staging pointers; fixed-max softmax (p = exp2(s)); partials atomicAdd'ed
// raw f32 (O,l) into acc/lacc; norm_kernel divides and casts.
__global__ __launch_bounds__(256, 3) void attn_kernel(
    const unsigned short* __restrict__ qh,   // [16][SEQ][64], scaled 0.125*log2e
    const unsigned short* __restrict__ kh,   // [16][SEQ][64]
    const unsigned short* __restrict__ vT,   // [16][64][SEQ]
    float* __restrict__ acc,                 // [SEQ][1024] f32 (zeroed)
    float* __restrict__ lacc)                // [SEQ][16] f32 (zeroed)
{
    __shared__ __align__(16) unsigned short Ks[2][64 * 64];
    __shared__ __align__(16) unsigned short Vs[2][64 * 64];   // [d][kv]
    const int h = blockIdx.x;
    const int qp = blockIdx.y;        // 0..15, paired with 31-qp
    const int s = blockIdx.z;         // kv third 0..2
    const int tid = threadIdx.x;
    const int lane = tid & 63;
    const int wave = tid >> 6;        // 0..3
    const int l31 = lane & 31;
    const int hi = lane >> 5;
    const int r7 = l31 & 7;

    const unsigned short* Kb = kh + (size_t)h * SEQ * 64;
    const unsigned short* Vb = vT + (size_t)h * 64 * SEQ;

    const int sr = tid >> 3;                    // 0..31
    const int scs = ((tid & 7) * 8) ^ ((sr & 7) * 8);

#pragma unroll 1
    for (int ph = 0; ph < 2; ph++) {
        const int qtp = ph ? (31 - qp) : qp;
        const int nt = 2 * qtp + 2;
        const int t0 = (nt * s) / 3;
        const int t1 = (nt * (s + 1)) / 3;
        if (t0 >= t1) continue;                 // block-uniform -> barrier-safe
        const int q0w = qtp * 128 + wave * 32;

        u16x8 qf[4];
        {
            const unsigned short* qb = qh + ((size_t)h * SEQ + q0w + l31) * 64 + hi * 8;
#pragma unroll
            for (int c = 0; c < 4; c++) qf[c] = *(const u16x8*)(qb + c * 16);
        }

        f32x16 o0 = {}, o1 = {};
        float l = 0.f;

        const unsigned short* kst = Kb + (size_t)(t0 * 64 + sr) * 64 + scs;
        const unsigned short* vst = Vb + (size_t)sr * SEQ + t0 * 64 + scs;

        gload_lds16(kst,            &Ks[0][tid * 8]);
        gload_lds16(kst + 32 * 64,  &Ks[0][2048 + tid * 8]);
        gload_lds16(vst,            &Vs[0][tid * 8]);
        gload_lds16(vst + 32 * SEQ, &Vs[0][2048 + tid * 8]);
        kst += 64 * 64;
        vst += 64;
        __syncthreads();

        int cur = 0;
        for (int kt = t0; kt < t1; kt++) {
            const int kv0 = kt * 64;
            if (kt + 1 < t1) {
                gload_lds16(kst,            &Ks[cur ^ 1][tid * 8]);
                gload_lds16(kst + 32 * 64,  &Ks[cur ^ 1][2048 + tid * 8]);
                gload_lds16(vst,            &Vs[cur ^ 1][tid * 8]);
                gload_lds16(vst + 32 * SEQ, &Vs[cur ^ 1][2048 + tid * 8]);
            }
            kst += 64 * 64;
            vst += 64;
            if (kv0 <= q0w + 31) {
                const unsigned short* ks0 = &Ks[cur][l31 * 64];
                const unsigned short* vs0 = &Vs[cur][l31 * 64];
                const unsigned short* ks1 = ks0 + 32 * 64;
                const unsigned short* vs1 = vs0 + 32 * 64;
                const bool half2 = (kv0 + 32 <= q0w + 31);
                const int q = q0w + l31;
                float ts;

                // ---------- S-half 0: kv rows kv0 .. kv0+31 ----------
                {
                    f32x16 st = {};
                    __builtin_amdgcn_s_setprio(1);
#pragma unroll
                    for (int c = 0; c < 4; c++) {
                        const int off = ((c * 2 + hi) ^ r7) * 8;
                        st = mfma_bf16_32x32x16(*(const u16x8*)(ks0 + off), qf[c], st);
                    }
                    __builtin_amdgcn_s_setprio(0);
                    if (kv0 + 31 > q0w) {
#pragma unroll
                        for (int r = 0; r < 16; r++) {
                            const int crow = (r & 3) + 8 * (r >> 2) + 4 * hi;
                            if (kv0 + crow > q) st[r] = -1e30f;
                        }
                    }
#pragma unroll
                    for (int r = 0; r < 16; r++) st[r] = exp2f(st[r]);
                    float u8[8];
#pragma unroll
                    for (int r = 0; r < 8; r++) u8[r] = st[r] + st[r + 8];
#pragma unroll
                    for (int r = 0; r < 4; r++) u8[r] += u8[r + 4];
                    ts = (u8[0] + u8[2]) + (u8[1] + u8[3]);

                    u16x8 paf[2];
#pragma unroll
                    for (int kk = 0; kk < 2; kk++) {
                        const int rb = kk * 8;
                        unsigned int a0 = cvtpk_bf16(st[rb + 0], st[rb + 1]);
                        unsigned int a1 = cvtpk_bf16(st[rb + 2], st[rb + 3]);
                        unsigned int b0 = cvtpk_bf16(st[rb + 4], st[rb + 5]);
                        unsigned int b1 = cvtpk_bf16(st[rb + 6], st[rb + 7]);
                        asm("v_permlane32_swap_b32 %0, %1" : "+v"(a0), "+v"(b0));
                        asm("v_permlane32_swap_b32 %0, %1" : "+v"(a1), "+v"(b1));
                        u32x4 w;
                        w[0] = a0; w[1] = a1; w[2] = b0; w[3] = b1;
                        paf[kk] = __builtin_bit_cast(u16x8, w);
                    }
                    __builtin_amdgcn_s_setprio(1);
#pragma unroll
                    for (int kk = 0; kk < 2; kk++) {
                        const int off = ((kk * 2 + hi) ^ r7) * 8;
                        u16x8 v0 = *(const u16x8*)(vs0 + off);
                        u16x8 v1 = *(const u16x8*)(vs1 + off);
                        o0 = mfma_bf16_32x32x16(paf[kk], v0, o0);
                        o1 = mfma_bf16_32x32x16(paf[kk], v1, o1);
                    }
                    __builtin_amdgcn_s_setprio(0);
                }

                // ---------- S-half 1: kv rows kv0+32 .. kv0+63 ----------
                if (half2) {
                    f32x16 st = {};
                    __builtin_amdgcn_s_setprio(1);
#pragma unroll
                    for (int c = 0; c < 4; c++) {
                        const int off = ((c * 2 + hi) ^ r7) * 8;
                        st = mfma_bf16_32x32x16(*(const u16x8*)(ks1 + off), qf[c], st);
                    }
                    __builtin_amdgcn_s_setprio(0);
                    if (kv0 + 63 > q0w) {
#pragma unroll
                        for (int r = 0; r < 16; r++) {
                            const int crow = (r & 3) + 8 * (r >> 2) + 4 * hi;
                            if (kv0 + 32 + crow > q) st[r] = -1e30f;
                        }
                    }
#pragma unroll
                    for (int r = 0; r < 16; r++) st[r] = exp2f(st[r]);
                    float u8[8];
#pragma unroll
                    for (int r = 0; r < 8; r++) u8[r] = st[r] + st[r + 8];
#pragma unroll
                    for (int r = 0; r < 4; r++) u8[r] += u8[r + 4];
                    ts += (u8[0] + u8[2]) + (u8[1] + u8[3]);

                    u16x8 paf[2];
#pragma unroll
                    for (int kk = 0; kk < 2; kk++) {
                        const int rb = kk * 8;
                        unsigned int a0 = cvtpk_bf16(st[rb + 0], st[rb + 1]);
                        unsigned int a1 = cvtpk_bf16(st[rb + 2], st[rb + 3]);
                        unsigned int b0 = cvtpk_bf16(st[rb + 4], st[rb + 5]);
                        unsigned int b1 = cvtpk_bf16(st[rb + 6], st[rb + 7]);
                        asm("v_permlane32_swap_b32 %0, %1" : "+v"(a0), "+v"(b0));
                        asm("v_permlane32_swap_b32 %0, %1" : "+v"(a1), "+v"(b1));
                        u32x4 w;
                        w[0] = a0; w[1] = a1; w[2] = b0; w[3] = b1;
                        paf[kk] = __builtin_bit_cast(u16x8, w);
                    }
                    __builtin_amdgcn_s_setprio(1);
#pragma unroll
                    for (int kk = 0; kk < 2; kk++) {
                        const int off = (((kk + 2) * 2 + hi) ^ r7) * 8;
                        u16x8 v0 = *(const u16x8*)(vs0 + off);
                        u16x8 v1 = *(const u16x8*)(vs1 + off);
                        o0 = mfma_bf16_32x32x16(paf[kk], v0, o0);
                        o1 = mfma_bf16_32x32x16(paf[kk], v1, o1);
                    }
                    __builtin_amdgcn_s_setprio(0);
                }

                ts += __shfl_xor(ts, 32);
                l += ts;
            }
            __syncthreads();
            cur ^= 1;
        }

        // epilogue: atomic-accumulate raw partial (O, l) in f32.
        if (t0 * 64 <= q0w + 31) {
#pragma unroll
            for (int r = 0; r < 16; r++) {
                const int crow = (r & 3) + 8 * (r >> 2) + 4 * hi;
                float* row = acc + (size_t)(q0w + crow) * 1024 + h * 64;
                atomicAdd(row + l31,      o0[r]);
                atomicAdd(row + 32 + l31, o1[r]);
            }
            if (hi == 0) atomicAdd(lacc + (size_t)(q0w + l31) * 16 + h, l);
        }
    }
}

// ---------------- normalize: yb = bf16(acc / lacc) ----------------
__global__ __launch_bounds__(256) void norm_kernel(
    const float* __restrict__ acc, const float* __restrict__ lacc,
    unsigned short* __restrict__ yb)
{
    const int i = blockIdx.x * 256 + threadIdx.x;   // quad index, 1,048,576 total
    const int t = i >> 8;
    const int h = (i & 255) >> 4;
    const float inv = 1.0f / lacc[t * 16 + h];
    f32x4 v = *(const f32x4*)(acc + (size_t)i * 4);
    u16x4 o;
#pragma unroll
    for (int j = 0; j < 4; j++) o[j] = f2bf(v[j] * inv);
    *(u16x4*)(yb + (size_t)i * 4) = o;
}

extern "C" void kernel_launch(void* const* d_in, const int* in_sizes, int n_in,
                              void* d_out, int out_size, void* d_ws, size_t ws_size,
                              hipStream_t stream) {
    (void)in_sizes; (void)n_in; (void)out_size; (void)ws_size;
    const float* x       = (const float*)d_in[0];
    const float* qkv_w   = (const float*)d_in[1];
    const float* lambdas = (const float*)d_in[2];
    const float* proj_w  = (const float*)d_in[3];

    char* ws = (char*)d_ws;
    // layout (80 MB peak); acc/lacc overlay x_bf+qkv_bf (dead before attn)
    unsigned short* x_bf   = (unsigned short*)(ws + 0);          //  8 MB [0,8M)
    unsigned short* qkv_bf = (unsigned short*)(ws + 8388608);    // 24 MB [8M,32M)
    unsigned short* qh     = (unsigned short*)(ws + 33554432);   //  8 MB
    unsigned short* kh     = (unsigned short*)(ws + 41943040);   //  8 MB
    unsigned short* vh     = (unsigned short*)(ws + 50331648);   //  8 MB
    unsigned short* vT     = (unsigned short*)(ws + 58720256);   //  8 MB
    unsigned short* wq_bf  = (unsigned short*)(ws + 67108864);   //  6 MB
    unsigned short* wp_bf  = (unsigned short*)(ws + 73400320);   //  2 MB
    unsigned short* yb     = (unsigned short*)(ws + 75497472);   //  8 MB
    float*          acc    = (float*)(ws + 0);                   // 16 MB [0,16.78M)
    float*          lacc   = (float*)(ws + 16777216);            // 256 KB

    cvt3_kernel<<<2048, 256, 0, stream>>>(x, x_bf, 1048576,
                                          qkv_w, wq_bf, 786432,
                                          proj_w, wp_bf, 262144);

    gemm_bt_kernel<1, 0><<<dim3(24, 32, 1), 256, 0, stream>>>(x_bf, wq_bf, qkv_bf, 4096, 3072, 1024, 1024);
    rope_norm_kernel<<<16384, 256, 0, stream>>>(qkv_bf, lambdas, qh, kh, vh);
    transpose_v_kernel<<<1024, 256, 0, stream>>>(vh, vT);

    // zero the f32 accumulators (x_bf/qkv_bf are dead now); capture-safe async
    hipMemsetAsync(ws, 0, 16777216 + 262144, stream);
    // zero d_out for the split-K proj GEMM's atomic accumulation
    hipMemsetAsync(d_out, 0, (size_t)out_size * 4, stream);

    attn_kernel<<<dim3(16, 16, 3), 256, 0, stream>>>(qh, kh, vT, acc, lacc);
    norm_kernel<<<4096, 256, 0, stream>>>(acc, lacc, yb);

    // proj GEMM, split-K=2: 512 blocks (2/CU) instead of 256 (1/CU)
    gemm_bt_kernel<0, 1><<<dim3(8, 32, 2), 256, 0, stream>>>(yb, wp_bf, d_out, 4096, 1024, 1024, 1024);
}

// Round 16
// 186.224 us; speedup vs baseline: 1.1191x; 1.1079x over previous
//
#include <hip/hip_runtime.h>
#include <stdint.h>

#define SEQ 4096
#define NHEAD 16
#define HDIM 64

typedef __attribute__((ext_vector_type(4))) float f32x4;
typedef __attribute__((ext_vector_type(16))) float f32x16;
typedef __attribute__((ext_vector_type(8))) __bf16 bf16x8;
typedef __attribute__((ext_vector_type(8))) unsigned short u16x8;
typedef __attribute__((ext_vector_type(4))) unsigned short u16x4;
typedef __attribute__((ext_vector_type(4))) unsigned int u32x4;

static __device__ __forceinline__ float bf2f(unsigned short u) {
    unsigned int x = ((unsigned int)u) << 16;
    return __builtin_bit_cast(float, x);
}
static __device__ __forceinline__ unsigned short f2bf(float f) {
    unsigned int u = __builtin_bit_cast(unsigned int, f);
    u += 0x7FFFu + ((u >> 16) & 1u);   // RNE
    return (unsigned short)(u >> 16);
}
static __device__ __forceinline__ f32x4 mfma_bf16_16x16x32(u16x8 a, u16x8 b, f32x4 c) {
    return __builtin_amdgcn_mfma_f32_16x16x32_bf16(
        __builtin_bit_cast(bf16x8, a), __builtin_bit_cast(bf16x8, b), c, 0, 0, 0);
}
static __device__ __forceinline__ f32x16 mfma_bf16_32x32x16(u16x8 a, u16x8 b, f32x16 c) {
    return __builtin_amdgcn_mfma_f32_32x32x16_bf16(
        __builtin_bit_cast(bf16x8, a), __builtin_bit_cast(bf16x8, b), c, 0, 0, 0);
}
static __device__ __forceinline__ void gload_lds16(const void* g, void* l) {
    __builtin_amdgcn_global_load_lds(
        (__attribute__((address_space(1))) unsigned int*)g,
        (__attribute__((address_space(3))) unsigned int*)l,
        16, 0, 0);
}
static __device__ __forceinline__ unsigned int cvtpk_bf16(float lo, float hi) {
    unsigned int r;
    asm("v_cvt_pk_bf16_f32 %0, %1, %2" : "=v"(r) : "v"(lo), "v"(hi));
    return r;
}

// ---------------- fused f32 -> bf16 convert (x, qkv_w, proj_w) ----------------
__global__ void cvt3_kernel(const float* __restrict__ s0, unsigned short* __restrict__ d0, int n0q,
                            const float* __restrict__ s1, unsigned short* __restrict__ d1, int n1q,
                            const float* __restrict__ s2, unsigned short* __restrict__ d2, int n2q)
{
    const int stride = gridDim.x * blockDim.x;
    const int total = n0q + n1q + n2q;
    for (int i = blockIdx.x * blockDim.x + threadIdx.x; i < total; i += stride) {
        const float* src; unsigned short* dst; int j;
        if (i < n0q)            { src = s0; dst = d0; j = i; }
        else if (i < n0q + n1q) { src = s1; dst = d1; j = i - n0q; }
        else                    { src = s2; dst = d2; j = i - n0q - n1q; }
        f32x4 v = *(const f32x4*)(src + (size_t)j * 4);
        u16x4 o;
#pragma unroll
        for (int k = 0; k < 4; k++) o[k] = f2bf(v[k]);
        *(u16x4*)(dst + (size_t)j * 4) = o;
    }
}

// ---------------- GEMM: C[M][N] = A[M][K(lda)] * B[N][K]^T ----------------
// Tile: BM=128 x BN (template). BN=128: 4 waves 2x2 of 64x64 (acc 4x4).
// BN=64: 4 waves 2x2 of 64x32 (acc 4x2), LDS 24KB, grid doubles -> 2 blk/CU
// for the occupancy-starved proj shape (was 256 blocks = 1 blk/CU).
template<int OUT_BF16, int BN>
__global__ __launch_bounds__(256) void gemm_bt_kernel(
    const unsigned short* __restrict__ A,
    const unsigned short* __restrict__ B,
    void* __restrict__ Cv,
    int M, int N, int K, int lda)
{
    constexpr int NJ = BN / 32;             // B-frags per wave / B-stage instrs
    __shared__ __align__(16) unsigned short As[128 * 64];
    __shared__ __align__(16) unsigned short Bs[BN * 64];
    const int tid = threadIdx.x;
    const int lane = tid & 63;
    const int wave = tid >> 6;
    const int wm = (wave >> 1) * 64;
    const int wn = (wave & 1) * (BN / 2);
    const int bm = blockIdx.y * 128, bn = blockIdx.x * BN;
    const int l15 = lane & 15, l4 = lane >> 4;

    f32x4 acc[4][NJ];
#pragma unroll
    for (int i = 0; i < 4; i++)
#pragma unroll
        for (int j = 0; j < NJ; j++) acc[i][j] = (f32x4){0.f, 0.f, 0.f, 0.f};

    const int srow = tid >> 3;
    const int scol = (tid & 7) * 8;
    const unsigned short* Ab = A + (size_t)(bm + srow) * lda + scol;
    const unsigned short* Bb = B + (size_t)(bn + srow) * K + scol;

    for (int kt = 0; kt < K; kt += 64) {
#pragma unroll
        for (int ci = 0; ci < 4; ci++)
            gload_lds16(Ab + (size_t)ci * 32 * lda + kt, &As[ci * 2048 + tid * 8]);
#pragma unroll
        for (int ci = 0; ci < NJ; ci++)
            gload_lds16(Bb + (size_t)ci * 32 * K + kt, &Bs[ci * 2048 + tid * 8]);
        __syncthreads();
#pragma unroll
        for (int ks = 0; ks < 2; ks++) {
            const int kc = ks * 32 + l4 * 8;
            u16x8 af[4], bfr[NJ];
#pragma unroll
            for (int i = 0; i < 4; i++)
                af[i] = *(const u16x8*)&As[(wm + i * 16 + l15) * 64 + kc];
#pragma unroll
            for (int j = 0; j < NJ; j++)
                bfr[j] = *(const u16x8*)&Bs[(wn + j * 16 + l15) * 64 + kc];
#pragma unroll
            for (int i = 0; i < 4; i++)
#pragma unroll
                for (int j = 0; j < NJ; j++)
                    acc[i][j] = mfma_bf16_16x16x32(af[i], bfr[j], acc[i][j]);
        }
        __syncthreads();
    }

    const int orow = bm + wm + l4 * 4;
    const int ocol = bn + wn + l15;
#pragma unroll
    for (int i = 0; i < 4; i++)
#pragma unroll
        for (int j = 0; j < NJ; j++)
#pragma unroll
            for (int r = 0; r < 4; r++) {
                size_t idx = (size_t)(orow + i * 16 + r) * N + (ocol + j * 16);
                if (OUT_BF16) ((unsigned short*)Cv)[idx] = f2bf(acc[i][j][r]);
                else          ((float*)Cv)[idx] = acc[i][j][r];
            }
}

// ---------------- RMS-norm + RoPE + lambda*v ----------------
// Q pre-scaled by (1/sqrt(D)) * log2(e) so attention exp runs in exp2 domain.
__global__ __launch_bounds__(256) void rope_norm_kernel(
    const unsigned short* __restrict__ qkv,   // [SEQ][3072] bf16
    const float* __restrict__ lambdas,
    unsigned short* __restrict__ qh,          // [16][SEQ][64]
    unsigned short* __restrict__ kh,
    unsigned short* __restrict__ vh)
{
    const int lane = threadIdx.x & 63;
    const int wave = threadIdx.x >> 6;
    const int vec = blockIdx.x * 4 + wave;
    const int t = vec >> 4;
    const int h = vec & 15;
    const size_t base = (size_t)t * 3072 + h * 64 + lane;
    float q = bf2f(qkv[base]);
    float k = bf2f(qkv[base + 1024]);
    float v = bf2f(qkv[base + 2048]);
    float sq = q * q, sk = k * k;
#pragma unroll
    for (int m = 1; m < 64; m <<= 1) {
        sq += __shfl_xor(sq, m);
        sk += __shfl_xor(sk, m);
    }
    q *= rsqrtf(sq * (1.0f / 64.0f) + 1e-6f);
    k *= rsqrtf(sk * (1.0f / 64.0f) + 1e-6f);
    const int i = lane & 31;
    float w = (i < 16) ? exp2f(-(10.0f / 15.0f) * (float)i) : 0.0f;
    float th = (float)t * w;
    float c = cosf(th), s = sinf(th);
    float qp = __shfl_xor(q, 32);
    float kp = __shfl_xor(k, 32);
    float sg = (lane < 32) ? s : -s;
    float qo = (q * c + qp * sg) * 0.1803368801111244f;  // 0.125 * log2(e)
    float ko = k * c + kp * sg;
    float vo = v * lambdas[0];
    const size_t o = ((size_t)h * SEQ + t) * 64 + lane;
    qh[o] = f2bf(qo);
    kh[o] = f2bf(ko);
    vh[o] = f2bf(vo);
}

// ---------------- V transpose: [h][t][d] -> [h][d][t] ----------------
__global__ __launch_bounds__(256) void transpose_v_kernel(
    const unsigned short* __restrict__ vh, unsigned short* __restrict__ vT)
{
    __shared__ __align__(16) unsigned short tile[64][72];
    const int h = blockIdx.x >> 6;
    const int tt = (blockIdx.x & 63) * 64;
    const int tid = threadIdx.x;
    const int row = tid >> 2;
    const int c0 = (tid & 3) * 16;
    const u16x8* src = (const u16x8*)(vh + ((size_t)h * SEQ + tt + row) * 64 + c0);
    u16x8 a = src[0], b = src[1];
#pragma unroll
    for (int j = 0; j < 8; j++) { tile[row][c0 + j] = a[j]; tile[row][c0 + 8 + j] = b[j]; }
    __syncthreads();
    u16x8 o0, o1;
#pragma unroll
    for (int j = 0; j < 8; j++) { o0[j] = tile[c0 + j][row]; o1[j] = tile[c0 + 8 + j][row]; }
    u16x8* dst = (u16x8*)(vT + ((size_t)h * 64 + row) * SEQ + tt + c0);
    dst[0] = o0; dst[1] = o1;
}

// ---------------- causal flash attention, swapped-QK^T 32x32 ----------------
// r10 verified structure (best measured: 79.9us attn, 190.8us total):
// block = (head, q-pair, kv-third); 256 thr = 4 waves x 32 q-rows; the two
// 32-kv S-halves processed sequentially (lower register pressure); running
// staging pointers; fixed-max softmax (p = exp2(s)); partials atomicAdd'ed
// raw f32 (O,l) into acc/lacc; norm_kernel divides and casts.
__global__ __launch_bounds__(256, 3) void attn_kernel(
    const unsigned short* __restrict__ qh,   // [16][SEQ][64], scaled 0.125*log2e
    const unsigned short* __restrict__ kh,   // [16][SEQ][64]
    const unsigned short* __restrict__ vT,   // [16][64][SEQ]
    float* __restrict__ acc,                 // [SEQ][1024] f32 (zeroed)
    float* __restrict__ lacc)                // [SEQ][16] f32 (zeroed)
{
    __shared__ __align__(16) unsigned short Ks[2][64 * 64];
    __shared__ __align__(16) unsigned short Vs[2][64 * 64];   // [d][kv]
    const int h = blockIdx.x;
    const int qp = blockIdx.y;        // 0..15, paired with 31-qp
    const int s = blockIdx.z;         // kv third 0..2
    const int tid = threadIdx.x;
    const int lane = tid & 63;
    const int wave = tid >> 6;        // 0..3
    const int l31 = lane & 31;
    const int hi = lane >> 5;
    const int r7 = l31 & 7;

    const unsigned short* Kb = kh + (size_t)h * SEQ * 64;
    const unsigned short* Vb = vT + (size_t)h * 64 * SEQ;

    const int sr = tid >> 3;                    // 0..31
    const int scs = ((tid & 7) * 8) ^ ((sr & 7) * 8);

#pragma unroll 1
    for (int ph = 0; ph < 2; ph++) {
        const int qtp = ph ? (31 - qp) : qp;
        const int nt = 2 * qtp + 2;
        const int t0 = (nt * s) / 3;
        const int t1 = (nt * (s + 1)) / 3;
        if (t0 >= t1) continue;                 // block-uniform -> barrier-safe
        const int q0w = qtp * 128 + wave * 32;

        u16x8 qf[4];
        {
            const unsigned short* qb = qh + ((size_t)h * SEQ + q0w + l31) * 64 + hi * 8;
#pragma unroll
            for (int c = 0; c < 4; c++) qf[c] = *(const u16x8*)(qb + c * 16);
        }

        f32x16 o0 = {}, o1 = {};
        float l = 0.f;

        const unsigned short* kst = Kb + (size_t)(t0 * 64 + sr) * 64 + scs;
        const unsigned short* vst = Vb + (size_t)sr * SEQ + t0 * 64 + scs;

        gload_lds16(kst,            &Ks[0][tid * 8]);
        gload_lds16(kst + 32 * 64,  &Ks[0][2048 + tid * 8]);
        gload_lds16(vst,            &Vs[0][tid * 8]);
        gload_lds16(vst + 32 * SEQ, &Vs[0][2048 + tid * 8]);
        kst += 64 * 64;
        vst += 64;
        __syncthreads();

        int cur = 0;
        for (int kt = t0; kt < t1; kt++) {
            const int kv0 = kt * 64;
            if (kt + 1 < t1) {
                gload_lds16(kst,            &Ks[cur ^ 1][tid * 8]);
                gload_lds16(kst + 32 * 64,  &Ks[cur ^ 1][2048 + tid * 8]);
                gload_lds16(vst,            &Vs[cur ^ 1][tid * 8]);
                gload_lds16(vst + 32 * SEQ, &Vs[cur ^ 1][2048 + tid * 8]);
            }
            kst += 64 * 64;
            vst += 64;
            if (kv0 <= q0w + 31) {
                const unsigned short* ks0 = &Ks[cur][l31 * 64];
                const unsigned short* vs0 = &Vs[cur][l31 * 64];
                const unsigned short* ks1 = ks0 + 32 * 64;
                const unsigned short* vs1 = vs0 + 32 * 64;
                const bool half2 = (kv0 + 32 <= q0w + 31);
                const int q = q0w + l31;
                float ts;

                // ---------- S-half 0: kv rows kv0 .. kv0+31 ----------
                {
                    f32x16 st = {};
                    __builtin_amdgcn_s_setprio(1);
#pragma unroll
                    for (int c = 0; c < 4; c++) {
                        const int off = ((c * 2 + hi) ^ r7) * 8;
                        st = mfma_bf16_32x32x16(*(const u16x8*)(ks0 + off), qf[c], st);
                    }
                    __builtin_amdgcn_s_setprio(0);
                    if (kv0 + 31 > q0w) {
#pragma unroll
                        for (int r = 0; r < 16; r++) {
                            const int crow = (r & 3) + 8 * (r >> 2) + 4 * hi;
                            if (kv0 + crow > q) st[r] = -1e30f;
                        }
                    }
#pragma unroll
                    for (int r = 0; r < 16; r++) st[r] = exp2f(st[r]);
                    float u8[8];
#pragma unroll
                    for (int r = 0; r < 8; r++) u8[r] = st[r] + st[r + 8];
#pragma unroll
                    for (int r = 0; r < 4; r++) u8[r] += u8[r + 4];
                    ts = (u8[0] + u8[2]) + (u8[1] + u8[3]);

                    u16x8 paf[2];
#pragma unroll
                    for (int kk = 0; kk < 2; kk++) {
                        const int rb = kk * 8;
                        unsigned int a0 = cvtpk_bf16(st[rb + 0], st[rb + 1]);
                        unsigned int a1 = cvtpk_bf16(st[rb + 2], st[rb + 3]);
                        unsigned int b0 = cvtpk_bf16(st[rb + 4], st[rb + 5]);
                        unsigned int b1 = cvtpk_bf16(st[rb + 6], st[rb + 7]);
                        asm("v_permlane32_swap_b32 %0, %1" : "+v"(a0), "+v"(b0));
                        asm("v_permlane32_swap_b32 %0, %1" : "+v"(a1), "+v"(b1));
                        u32x4 w;
                        w[0] = a0; w[1] = a1; w[2] = b0; w[3] = b1;
                        paf[kk] = __builtin_bit_cast(u16x8, w);
                    }
                    __builtin_amdgcn_s_setprio(1);
#pragma unroll
                    for (int kk = 0; kk < 2; kk++) {
                        const int off = ((kk * 2 + hi) ^ r7) * 8;
                        u16x8 v0 = *(const u16x8*)(vs0 + off);
                        u16x8 v1 = *(const u16x8*)(vs1 + off);
                        o0 = mfma_bf16_32x32x16(paf[kk], v0, o0);
                        o1 = mfma_bf16_32x32x16(paf[kk], v1, o1);
                    }
                    __builtin_amdgcn_s_setprio(0);
                }

                // ---------- S-half 1: kv rows kv0+32 .. kv0+63 ----------
                if (half2) {
                    f32x16 st = {};
                    __builtin_amdgcn_s_setprio(1);
#pragma unroll
                    for (int c = 0; c < 4; c++) {
                        const int off = ((c * 2 + hi) ^ r7) * 8;
                        st = mfma_bf16_32x32x16(*(const u16x8*)(ks1 + off), qf[c], st);
                    }
                    __builtin_amdgcn_s_setprio(0);
                    if (kv0 + 63 > q0w) {
#pragma unroll
                        for (int r = 0; r < 16; r++) {
                            const int crow = (r & 3) + 8 * (r >> 2) + 4 * hi;
                            if (kv0 + 32 + crow > q) st[r] = -1e30f;
                        }
                    }
#pragma unroll
                    for (int r = 0; r < 16; r++) st[r] = exp2f(st[r]);
                    float u8[8];
#pragma unroll
                    for (int r = 0; r < 8; r++) u8[r] = st[r] + st[r + 8];
#pragma unroll
                    for (int r = 0; r < 4; r++) u8[r] += u8[r + 4];
                    ts += (u8[0] + u8[2]) + (u8[1] + u8[3]);

                    u16x8 paf[2];
#pragma unroll
                    for (int kk = 0; kk < 2; kk++) {
                        const int rb = kk * 8;
                        unsigned int a0 = cvtpk_bf16(st[rb + 0], st[rb + 1]);
                        unsigned int a1 = cvtpk_bf16(st[rb + 2], st[rb + 3]);
                        unsigned int b0 = cvtpk_bf16(st[rb + 4], st[rb + 5]);
                        unsigned int b1 = cvtpk_bf16(st[rb + 6], st[rb + 7]);
                        asm("v_permlane32_swap_b32 %0, %1" : "+v"(a0), "+v"(b0));
                        asm("v_permlane32_swap_b32 %0, %1" : "+v"(a1), "+v"(b1));
                        u32x4 w;
                        w[0] = a0; w[1] = a1; w[2] = b0; w[3] = b1;
                        paf[kk] = __builtin_bit_cast(u16x8, w);
                    }
                    __builtin_amdgcn_s_setprio(1);
#pragma unroll
                    for (int kk = 0; kk < 2; kk++) {
                        const int off = (((kk + 2) * 2 + hi) ^ r7) * 8;
                        u16x8 v0 = *(const u16x8*)(vs0 + off);
                        u16x8 v1 = *(const u16x8*)(vs1 + off);
                        o0 = mfma_bf16_32x32x16(paf[kk], v0, o0);
                        o1 = mfma_bf16_32x32x16(paf[kk], v1, o1);
                    }
                    __builtin_amdgcn_s_setprio(0);
                }

                ts += __shfl_xor(ts, 32);
                l += ts;
            }
            __syncthreads();
            cur ^= 1;
        }

        // epilogue: atomic-accumulate raw partial (O, l) in f32.
        if (t0 * 64 <= q0w + 31) {
#pragma unroll
            for (int r = 0; r < 16; r++) {
                const int crow = (r & 3) + 8 * (r >> 2) + 4 * hi;
                float* row = acc + (size_t)(q0w + crow) * 1024 + h * 64;
                atomicAdd(row + l31,      o0[r]);
                atomicAdd(row + 32 + l31, o1[r]);
            }
            if (hi == 0) atomicAdd(lacc + (size_t)(q0w + l31) * 16 + h, l);
        }
    }
}

// ---------------- normalize: yb = bf16(acc / lacc) ----------------
__global__ __launch_bounds__(256) void norm_kernel(
    const float* __restrict__ acc, const float* __restrict__ lacc,
    unsigned short* __restrict__ yb)
{
    const int i = blockIdx.x * 256 + threadIdx.x;   // quad index, 1,048,576 total
    const int t = i >> 8;
    const int h = (i & 255) >> 4;
    const float inv = 1.0f / lacc[t * 16 + h];
    f32x4 v = *(const f32x4*)(acc + (size_t)i * 4);
    u16x4 o;
#pragma unroll
    for (int j = 0; j < 4; j++) o[j] = f2bf(v[j] * inv);
    *(u16x4*)(yb + (size_t)i * 4) = o;
}

extern "C" void kernel_launch(void* const* d_in, const int* in_sizes, int n_in,
                              void* d_out, int out_size, void* d_ws, size_t ws_size,
                              hipStream_t stream) {
    (void)in_sizes; (void)n_in; (void)out_size; (void)ws_size;
    const float* x       = (const float*)d_in[0];
    const float* qkv_w   = (const float*)d_in[1];
    const float* lambdas = (const float*)d_in[2];
    const float* proj_w  = (const float*)d_in[3];

    char* ws = (char*)d_ws;
    // layout (80 MB peak); acc/lacc overlay x_bf+qkv_bf (dead before attn)
    unsigned short* x_bf   = (unsigned short*)(ws + 0);          //  8 MB [0,8M)
    unsigned short* qkv_bf = (unsigned short*)(ws + 8388608);    // 24 MB [8M,32M)
    unsigned short* qh     = (unsigned short*)(ws + 33554432);   //  8 MB
    unsigned short* kh     = (unsigned short*)(ws + 41943040);   //  8 MB
    unsigned short* vh     = (unsigned short*)(ws + 50331648);   //  8 MB
    unsigned short* vT     = (unsigned short*)(ws + 58720256);   //  8 MB
    unsigned short* wq_bf  = (unsigned short*)(ws + 67108864);   //  6 MB
    unsigned short* wp_bf  = (unsigned short*)(ws + 73400320);   //  2 MB
    unsigned short* yb     = (unsigned short*)(ws + 75497472);   //  8 MB
    float*          acc    = (float*)(ws + 0);                   // 16 MB [0,16.78M)
    float*          lacc   = (float*)(ws + 16777216);            // 256 KB

    cvt3_kernel<<<2048, 256, 0, stream>>>(x, x_bf, 1048576,
                                          qkv_w, wq_bf, 786432,
                                          proj_w, wp_bf, 262144);

    gemm_bt_kernel<1, 128><<<dim3(24, 32), 256, 0, stream>>>(x_bf, wq_bf, qkv_bf, 4096, 3072, 1024, 1024);
    rope_norm_kernel<<<16384, 256, 0, stream>>>(qkv_bf, lambdas, qh, kh, vh);
    transpose_v_kernel<<<1024, 256, 0, stream>>>(vh, vT);

    // zero the f32 accumulators (x_bf/qkv_bf are dead now); capture-safe async
    hipMemsetAsync(ws, 0, 16777216 + 262144, stream);

    attn_kernel<<<dim3(16, 16, 3), 256, 0, stream>>>(qh, kh, vT, acc, lacc);
    norm_kernel<<<4096, 256, 0, stream>>>(acc, lacc, yb);

    // proj GEMM: BM=128 x BN=64 tile -> 512 blocks = 2 blk/CU (was 256 = 1/CU)
    gemm_bt_kernel<0, 64><<<dim3(16, 32), 256, 0, stream>>>(yb, wp_bf, d_out, 4096, 1024, 1024, 1024);
}

// Round 17
// 180.359 us; speedup vs baseline: 1.1555x; 1.0325x over previous
//
#include <hip/hip_runtime.h>
#include <stdint.h>

#define SEQ 4096
#define NHEAD 16
#define HDIM 64

typedef __attribute__((ext_vector_type(4))) float f32x4;
typedef __attribute__((ext_vector_type(16))) float f32x16;
typedef __attribute__((ext_vector_type(8))) __bf16 bf16x8;
typedef __attribute__((ext_vector_type(8))) unsigned short u16x8;
typedef __attribute__((ext_vector_type(4))) unsigned short u16x4;
typedef __attribute__((ext_vector_type(4))) unsigned int u32x4;

static __device__ __forceinline__ float bf2f(unsigned short u) {
    unsigned int x = ((unsigned int)u) << 16;
    return __builtin_bit_cast(float, x);
}
static __device__ __forceinline__ unsigned short f2bf(float f) {
    unsigned int u = __builtin_bit_cast(unsigned int, f);
    u += 0x7FFFu + ((u >> 16) & 1u);   // RNE
    return (unsigned short)(u >> 16);
}
static __device__ __forceinline__ f32x4 mfma_bf16_16x16x32(u16x8 a, u16x8 b, f32x4 c) {
    return __builtin_amdgcn_mfma_f32_16x16x32_bf16(
        __builtin_bit_cast(bf16x8, a), __builtin_bit_cast(bf16x8, b), c, 0, 0, 0);
}
static __device__ __forceinline__ f32x16 mfma_bf16_32x32x16(u16x8 a, u16x8 b, f32x16 c) {
    return __builtin_amdgcn_mfma_f32_32x32x16_bf16(
        __builtin_bit_cast(bf16x8, a), __builtin_bit_cast(bf16x8, b), c, 0, 0, 0);
}
static __device__ __forceinline__ void gload_lds16(const void* g, void* l) {
    __builtin_amdgcn_global_load_lds(
        (__attribute__((address_space(1))) unsigned int*)g,
        (__attribute__((address_space(3))) unsigned int*)l,
        16, 0, 0);
}
static __device__ __forceinline__ unsigned int cvtpk_bf16(float lo, float hi) {
    unsigned int r;
    asm("v_cvt_pk_bf16_f32 %0, %1, %2" : "=v"(r) : "v"(lo), "v"(hi));
    return r;
}

// ---------------- fused f32 -> bf16 convert (x, qkv_w, proj_w) ----------------
__global__ void cvt3_kernel(const float* __restrict__ s0, unsigned short* __restrict__ d0, int n0q,
                            const float* __restrict__ s1, unsigned short* __restrict__ d1, int n1q,
                            const float* __restrict__ s2, unsigned short* __restrict__ d2, int n2q)
{
    const int stride = gridDim.x * blockDim.x;
    const int total = n0q + n1q + n2q;
    for (int i = blockIdx.x * blockDim.x + threadIdx.x; i < total; i += stride) {
        const float* src; unsigned short* dst; int j;
        if (i < n0q)            { src = s0; dst = d0; j = i; }
        else if (i < n0q + n1q) { src = s1; dst = d1; j = i - n0q; }
        else                    { src = s2; dst = d2; j = i - n0q - n1q; }
        f32x4 v = *(const f32x4*)(src + (size_t)j * 4);
        u16x4 o;
#pragma unroll
        for (int k = 0; k < 4; k++) o[k] = f2bf(v[k]);
        *(u16x4*)(dst + (size_t)j * 4) = o;
    }
}

// ---------------- GEMM: C[M][N] = A[M][K(lda)] * B[N][K]^T ----------------
// Tile: BM=128 x BN (template). BN=128: 4 waves 2x2 of 64x64 (acc 4x4),
// LDS 32KB, 3 blk/CU. BN=64: 4 waves 2x2 of 64x32 (acc 4x2), LDS 24KB,
// grid doubles in N -> 6 blk/CU (LDS-limited) = 6 waves/SIMD. Total staging
// traffic is invariant under the split; A/B are L2/L3-resident.
template<int OUT_BF16, int BN>
__global__ __launch_bounds__(256) void gemm_bt_kernel(
    const unsigned short* __restrict__ A,
    const unsigned short* __restrict__ B,
    void* __restrict__ Cv,
    int M, int N, int K, int lda)
{
    constexpr int NJ = BN / 32;             // B-frags per wave / B-stage instrs
    __shared__ __align__(16) unsigned short As[128 * 64];
    __shared__ __align__(16) unsigned short Bs[BN * 64];
    const int tid = threadIdx.x;
    const int lane = tid & 63;
    const int wave = tid >> 6;
    const int wm = (wave >> 1) * 64;
    const int wn = (wave & 1) * (BN / 2);
    const int bm = blockIdx.y * 128, bn = blockIdx.x * BN;
    const int l15 = lane & 15, l4 = lane >> 4;

    f32x4 acc[4][NJ];
#pragma unroll
    for (int i = 0; i < 4; i++)
#pragma unroll
        for (int j = 0; j < NJ; j++) acc[i][j] = (f32x4){0.f, 0.f, 0.f, 0.f};

    const int srow = tid >> 3;
    const int scol = (tid & 7) * 8;
    const unsigned short* Ab = A + (size_t)(bm + srow) * lda + scol;
    const unsigned short* Bb = B + (size_t)(bn + srow) * K + scol;

    for (int kt = 0; kt < K; kt += 64) {
#pragma unroll
        for (int ci = 0; ci < 4; ci++)
            gload_lds16(Ab + (size_t)ci * 32 * lda + kt, &As[ci * 2048 + tid * 8]);
#pragma unroll
        for (int ci = 0; ci < NJ; ci++)
            gload_lds16(Bb + (size_t)ci * 32 * K + kt, &Bs[ci * 2048 + tid * 8]);
        __syncthreads();
#pragma unroll
        for (int ks = 0; ks < 2; ks++) {
            const int kc = ks * 32 + l4 * 8;
            u16x8 af[4], bfr[NJ];
#pragma unroll
            for (int i = 0; i < 4; i++)
                af[i] = *(const u16x8*)&As[(wm + i * 16 + l15) * 64 + kc];
#pragma unroll
            for (int j = 0; j < NJ; j++)
                bfr[j] = *(const u16x8*)&Bs[(wn + j * 16 + l15) * 64 + kc];
#pragma unroll
            for (int i = 0; i < 4; i++)
#pragma unroll
                for (int j = 0; j < NJ; j++)
                    acc[i][j] = mfma_bf16_16x16x32(af[i], bfr[j], acc[i][j]);
        }
        __syncthreads();
    }

    const int orow = bm + wm + l4 * 4;
    const int ocol = bn + wn + l15;
#pragma unroll
    for (int i = 0; i < 4; i++)
#pragma unroll
        for (int j = 0; j < NJ; j++)
#pragma unroll
            for (int r = 0; r < 4; r++) {
                size_t idx = (size_t)(orow + i * 16 + r) * N + (ocol + j * 16);
                if (OUT_BF16) ((unsigned short*)Cv)[idx] = f2bf(acc[i][j][r]);
                else          ((float*)Cv)[idx] = acc[i][j][r];
            }
}

// ---------------- RMS-norm + RoPE + lambda*v ----------------
// Q pre-scaled by (1/sqrt(D)) * log2(e) so attention exp runs in exp2 domain.
__global__ __launch_bounds__(256) void rope_norm_kernel(
    const unsigned short* __restrict__ qkv,   // [SEQ][3072] bf16
    const float* __restrict__ lambdas,
    unsigned short* __restrict__ qh,          // [16][SEQ][64]
    unsigned short* __restrict__ kh,
    unsigned short* __restrict__ vh)
{
    const int lane = threadIdx.x & 63;
    const int wave = threadIdx.x >> 6;
    const int vec = blockIdx.x * 4 + wave;
    const int t = vec >> 4;
    const int h = vec & 15;
    const size_t base = (size_t)t * 3072 + h * 64 + lane;
    float q = bf2f(qkv[base]);
    float k = bf2f(qkv[base + 1024]);
    float v = bf2f(qkv[base + 2048]);
    float sq = q * q, sk = k * k;
#pragma unroll
    for (int m = 1; m < 64; m <<= 1) {
        sq += __shfl_xor(sq, m);
        sk += __shfl_xor(sk, m);
    }
    q *= rsqrtf(sq * (1.0f / 64.0f) + 1e-6f);
    k *= rsqrtf(sk * (1.0f / 64.0f) + 1e-6f);
    const int i = lane & 31;
    float w = (i < 16) ? exp2f(-(10.0f / 15.0f) * (float)i) : 0.0f;
    float th = (float)t * w;
    float c = cosf(th), s = sinf(th);
    float qp = __shfl_xor(q, 32);
    float kp = __shfl_xor(k, 32);
    float sg = (lane < 32) ? s : -s;
    float qo = (q * c + qp * sg) * 0.1803368801111244f;  // 0.125 * log2(e)
    float ko = k * c + kp * sg;
    float vo = v * lambdas[0];
    const size_t o = ((size_t)h * SEQ + t) * 64 + lane;
    qh[o] = f2bf(qo);
    kh[o] = f2bf(ko);
    vh[o] = f2bf(vo);
}

// ---------------- V transpose: [h][t][d] -> [h][d][t] ----------------
__global__ __launch_bounds__(256) void transpose_v_kernel(
    const unsigned short* __restrict__ vh, unsigned short* __restrict__ vT)
{
    __shared__ __align__(16) unsigned short tile[64][72];
    const int h = blockIdx.x >> 6;
    const int tt = (blockIdx.x & 63) * 64;
    const int tid = threadIdx.x;
    const int row = tid >> 2;
    const int c0 = (tid & 3) * 16;
    const u16x8* src = (const u16x8*)(vh + ((size_t)h * SEQ + tt + row) * 64 + c0);
    u16x8 a = src[0], b = src[1];
#pragma unroll
    for (int j = 0; j < 8; j++) { tile[row][c0 + j] = a[j]; tile[row][c0 + 8 + j] = b[j]; }
    __syncthreads();
    u16x8 o0, o1;
#pragma unroll
    for (int j = 0; j < 8; j++) { o0[j] = tile[c0 + j][row]; o1[j] = tile[c0 + 8 + j][row]; }
    u16x8* dst = (u16x8*)(vT + ((size_t)h * 64 + row) * SEQ + tt + c0);
    dst[0] = o0; dst[1] = o1;
}

// ---------------- causal flash attention, swapped-QK^T 32x32 ----------------
// r10 verified structure (79.5-79.9us attn):
// block = (head, q-pair, kv-third); 256 thr = 4 waves x 32 q-rows; the two
// 32-kv S-halves processed sequentially (lower register pressure); running
// staging pointers; fixed-max softmax (p = exp2(s)); partials atomicAdd'ed
// raw f32 (O,l) into acc/lacc; norm_kernel divides and casts.
__global__ __launch_bounds__(256, 3) void attn_kernel(
    const unsigned short* __restrict__ qh,   // [16][SEQ][64], scaled 0.125*log2e
    const unsigned short* __restrict__ kh,   // [16][SEQ][64]
    const unsigned short* __restrict__ vT,   // [16][64][SEQ]
    float* __restrict__ acc,                 // [SEQ][1024] f32 (zeroed)
    float* __restrict__ lacc)                // [SEQ][16] f32 (zeroed)
{
    __shared__ __align__(16) unsigned short Ks[2][64 * 64];
    __shared__ __align__(16) unsigned short Vs[2][64 * 64];   // [d][kv]
    const int h = blockIdx.x;
    const int qp = blockIdx.y;        // 0..15, paired with 31-qp
    const int s = blockIdx.z;         // kv third 0..2
    const int tid = threadIdx.x;
    const int lane = tid & 63;
    const int wave = tid >> 6;        // 0..3
    const int l31 = lane & 31;
    const int hi = lane >> 5;
    const int r7 = l31 & 7;

    const unsigned short* Kb = kh + (size_t)h * SEQ * 64;
    const unsigned short* Vb = vT + (size_t)h * 64 * SEQ;

    const int sr = tid >> 3;                    // 0..31
    const int scs = ((tid & 7) * 8) ^ ((sr & 7) * 8);

#pragma unroll 1
    for (int ph = 0; ph < 2; ph++) {
        const int qtp = ph ? (31 - qp) : qp;
        const int nt = 2 * qtp + 2;
        const int t0 = (nt * s) / 3;
        const int t1 = (nt * (s + 1)) / 3;
        if (t0 >= t1) continue;                 // block-uniform -> barrier-safe
        const int q0w = qtp * 128 + wave * 32;

        u16x8 qf[4];
        {
            const unsigned short* qb = qh + ((size_t)h * SEQ + q0w + l31) * 64 + hi * 8;
#pragma unroll
            for (int c = 0; c < 4; c++) qf[c] = *(const u16x8*)(qb + c * 16);
        }

        f32x16 o0 = {}, o1 = {};
        float l = 0.f;

        const unsigned short* kst = Kb + (size_t)(t0 * 64 + sr) * 64 + scs;
        const unsigned short* vst = Vb + (size_t)sr * SEQ + t0 * 64 + scs;

        gload_lds16(kst,            &Ks[0][tid * 8]);
        gload_lds16(kst + 32 * 64,  &Ks[0][2048 + tid * 8]);
        gload_lds16(vst,            &Vs[0][tid * 8]);
        gload_lds16(vst + 32 * SEQ, &Vs[0][2048 + tid * 8]);
        kst += 64 * 64;
        vst += 64;
        __syncthreads();

        int cur = 0;
        for (int kt = t0; kt < t1; kt++) {
            const int kv0 = kt * 64;
            if (kt + 1 < t1) {
                gload_lds16(kst,            &Ks[cur ^ 1][tid * 8]);
                gload_lds16(kst + 32 * 64,  &Ks[cur ^ 1][2048 + tid * 8]);
                gload_lds16(vst,            &Vs[cur ^ 1][tid * 8]);
                gload_lds16(vst + 32 * SEQ, &Vs[cur ^ 1][2048 + tid * 8]);
            }
            kst += 64 * 64;
            vst += 64;
            if (kv0 <= q0w + 31) {
                const unsigned short* ks0 = &Ks[cur][l31 * 64];
                const unsigned short* vs0 = &Vs[cur][l31 * 64];
                const unsigned short* ks1 = ks0 + 32 * 64;
                const unsigned short* vs1 = vs0 + 32 * 64;
                const bool half2 = (kv0 + 32 <= q0w + 31);
                const int q = q0w + l31;
                float ts;

                // ---------- S-half 0: kv rows kv0 .. kv0+31 ----------
                {
                    f32x16 st = {};
                    __builtin_amdgcn_s_setprio(1);
#pragma unroll
                    for (int c = 0; c < 4; c++) {
                        const int off = ((c * 2 + hi) ^ r7) * 8;
                        st = mfma_bf16_32x32x16(*(const u16x8*)(ks0 + off), qf[c], st);
                    }
                    __builtin_amdgcn_s_setprio(0);
                    if (kv0 + 31 > q0w) {
#pragma unroll
                        for (int r = 0; r < 16; r++) {
                            const int crow = (r & 3) + 8 * (r >> 2) + 4 * hi;
                            if (kv0 + crow > q) st[r] = -1e30f;
                        }
                    }
#pragma unroll
                    for (int r = 0; r < 16; r++) st[r] = exp2f(st[r]);
                    float u8[8];
#pragma unroll
                    for (int r = 0; r < 8; r++) u8[r] = st[r] + st[r + 8];
#pragma unroll
                    for (int r = 0; r < 4; r++) u8[r] += u8[r + 4];
                    ts = (u8[0] + u8[2]) + (u8[1] + u8[3]);

                    u16x8 paf[2];
#pragma unroll
                    for (int kk = 0; kk < 2; kk++) {
                        const int rb = kk * 8;
                        unsigned int a0 = cvtpk_bf16(st[rb + 0], st[rb + 1]);
                        unsigned int a1 = cvtpk_bf16(st[rb + 2], st[rb + 3]);
                        unsigned int b0 = cvtpk_bf16(st[rb + 4], st[rb + 5]);
                        unsigned int b1 = cvtpk_bf16(st[rb + 6], st[rb + 7]);
                        asm("v_permlane32_swap_b32 %0, %1" : "+v"(a0), "+v"(b0));
                        asm("v_permlane32_swap_b32 %0, %1" : "+v"(a1), "+v"(b1));
                        u32x4 w;
                        w[0] = a0; w[1] = a1; w[2] = b0; w[3] = b1;
                        paf[kk] = __builtin_bit_cast(u16x8, w);
                    }
                    __builtin_amdgcn_s_setprio(1);
#pragma unroll
                    for (int kk = 0; kk < 2; kk++) {
                        const int off = ((kk * 2 + hi) ^ r7) * 8;
                        u16x8 v0 = *(const u16x8*)(vs0 + off);
                        u16x8 v1 = *(const u16x8*)(vs1 + off);
                        o0 = mfma_bf16_32x32x16(paf[kk], v0, o0);
                        o1 = mfma_bf16_32x32x16(paf[kk], v1, o1);
                    }
                    __builtin_amdgcn_s_setprio(0);
                }

                // ---------- S-half 1: kv rows kv0+32 .. kv0+63 ----------
                if (half2) {
                    f32x16 st = {};
                    __builtin_amdgcn_s_setprio(1);
#pragma unroll
                    for (int c = 0; c < 4; c++) {
                        const int off = ((c * 2 + hi) ^ r7) * 8;
                        st = mfma_bf16_32x32x16(*(const u16x8*)(ks1 + off), qf[c], st);
                    }
                    __builtin_amdgcn_s_setprio(0);
                    if (kv0 + 63 > q0w) {
#pragma unroll
                        for (int r = 0; r < 16; r++) {
                            const int crow = (r & 3) + 8 * (r >> 2) + 4 * hi;
                            if (kv0 + 32 + crow > q) st[r] = -1e30f;
                        }
                    }
#pragma unroll
                    for (int r = 0; r < 16; r++) st[r] = exp2f(st[r]);
                    float u8[8];
#pragma unroll
                    for (int r = 0; r < 8; r++) u8[r] = st[r] + st[r + 8];
#pragma unroll
                    for (int r = 0; r < 4; r++) u8[r] += u8[r + 4];
                    ts += (u8[0] + u8[2]) + (u8[1] + u8[3]);

                    u16x8 paf[2];
#pragma unroll
                    for (int kk = 0; kk < 2; kk++) {
                        const int rb = kk * 8;
                        unsigned int a0 = cvtpk_bf16(st[rb + 0], st[rb + 1]);
                        unsigned int a1 = cvtpk_bf16(st[rb + 2], st[rb + 3]);
                        unsigned int b0 = cvtpk_bf16(st[rb + 4], st[rb + 5]);
                        unsigned int b1 = cvtpk_bf16(st[rb + 6], st[rb + 7]);
                        asm("v_permlane32_swap_b32 %0, %1" : "+v"(a0), "+v"(b0));
                        asm("v_permlane32_swap_b32 %0, %1" : "+v"(a1), "+v"(b1));
                        u32x4 w;
                        w[0] = a0; w[1] = a1; w[2] = b0; w[3] = b1;
                        paf[kk] = __builtin_bit_cast(u16x8, w);
                    }
                    __builtin_amdgcn_s_setprio(1);
#pragma unroll
                    for (int kk = 0; kk < 2; kk++) {
                        const int off = (((kk + 2) * 2 + hi) ^ r7) * 8;
                        u16x8 v0 = *(const u16x8*)(vs0 + off);
                        u16x8 v1 = *(const u16x8*)(vs1 + off);
                        o0 = mfma_bf16_32x32x16(paf[kk], v0, o0);
                        o1 = mfma_bf16_32x32x16(paf[kk], v1, o1);
                    }
                    __builtin_amdgcn_s_setprio(0);
                }

                ts += __shfl_xor(ts, 32);
                l += ts;
            }
            __syncthreads();
            cur ^= 1;
        }

        // epilogue: atomic-accumulate raw partial (O, l) in f32.
        if (t0 * 64 <= q0w + 31) {
#pragma unroll
            for (int r = 0; r < 16; r++) {
                const int crow = (r & 3) + 8 * (r >> 2) + 4 * hi;
                float* row = acc + (size_t)(q0w + crow) * 1024 + h * 64;
                atomicAdd(row + l31,      o0[r]);
                atomicAdd(row + 32 + l31, o1[r]);
            }
            if (hi == 0) atomicAdd(lacc + (size_t)(q0w + l31) * 16 + h, l);
        }
    }
}

// ---------------- normalize: yb = bf16(acc / lacc) ----------------
__global__ __launch_bounds__(256) void norm_kernel(
    const float* __restrict__ acc, const float* __restrict__ lacc,
    unsigned short* __restrict__ yb)
{
    const int i = blockIdx.x * 256 + threadIdx.x;   // quad index, 1,048,576 total
    const int t = i >> 8;
    const int h = (i & 255) >> 4;
    const float inv = 1.0f / lacc[t * 16 + h];
    f32x4 v = *(const f32x4*)(acc + (size_t)i * 4);
    u16x4 o;
#pragma unroll
    for (int j = 0; j < 4; j++) o[j] = f2bf(v[j] * inv);
    *(u16x4*)(yb + (size_t)i * 4) = o;
}

extern "C" void kernel_launch(void* const* d_in, const int* in_sizes, int n_in,
                              void* d_out, int out_size, void* d_ws, size_t ws_size,
                              hipStream_t stream) {
    (void)in_sizes; (void)n_in; (void)out_size; (void)ws_size;
    const float* x       = (const float*)d_in[0];
    const float* qkv_w   = (const float*)d_in[1];
    const float* lambdas = (const float*)d_in[2];
    const float* proj_w  = (const float*)d_in[3];

    char* ws = (char*)d_ws;
    // layout (80 MB peak); acc/lacc overlay x_bf+qkv_bf (dead before attn)
    unsigned short* x_bf   = (unsigned short*)(ws + 0);          //  8 MB [0,8M)
    unsigned short* qkv_bf = (unsigned short*)(ws + 8388608);    // 24 MB [8M,32M)
    unsigned short* qh     = (unsigned short*)(ws + 33554432);   //  8 MB
    unsigned short* kh     = (unsigned short*)(ws + 41943040);   //  8 MB
    unsigned short* vh     = (unsigned short*)(ws + 50331648);   //  8 MB
    unsigned short* vT     = (unsigned short*)(ws + 58720256);   //  8 MB
    unsigned short* wq_bf  = (unsigned short*)(ws + 67108864);   //  6 MB
    unsigned short* wp_bf  = (unsigned short*)(ws + 73400320);   //  2 MB
    unsigned short* yb     = (unsigned short*)(ws + 75497472);   //  8 MB
    float*          acc    = (float*)(ws + 0);                   // 16 MB [0,16.78M)
    float*          lacc   = (float*)(ws + 16777216);            // 256 KB

    cvt3_kernel<<<2048, 256, 0, stream>>>(x, x_bf, 1048576,
                                          qkv_w, wq_bf, 786432,
                                          proj_w, wp_bf, 262144);

    // QKV GEMM: BM=128 x BN=64 -> grid 48x32 = 1536 blocks = 6 blk/CU
    gemm_bt_kernel<1, 64><<<dim3(48, 32), 256, 0, stream>>>(x_bf, wq_bf, qkv_bf, 4096, 3072, 1024, 1024);
    rope_norm_kernel<<<16384, 256, 0, stream>>>(qkv_bf, lambdas, qh, kh, vh);
    transpose_v_kernel<<<1024, 256, 0, stream>>>(vh, vT);

    // zero the f32 accumulators (x_bf/qkv_bf are dead now); capture-safe async
    hipMemsetAsync(ws, 0, 16777216 + 262144, stream);

    attn_kernel<<<dim3(16, 16, 3), 256, 0, stream>>>(qh, kh, vT, acc, lacc);
    norm_kernel<<<4096, 256, 0, stream>>>(acc, lacc, yb);

    // proj GEMM: BM=128 x BN=64 tile -> 512 blocks = 2 blk/CU
    gemm_bt_kernel<0, 64><<<dim3(16, 32), 256, 0, stream>>>(yb, wp_bf, d_out, 4096, 1024, 1024, 1024);
}